// Round 9
// baseline (257.374 us; speedup 1.0000x reference)
//
#include <hip/hip_runtime.h>
#include <hip/hip_bf16.h>

#define PI_F 3.14159265f

// Flat index convention: state.reshape((2,)*16) => qubit q <-> flat bit j = 15-q.
// Per layer: Ry(all f), CNOT chain (15->14),(14->13),...,(1->0),(0->15), Rz(all f).
// Measurement <Z_q> q=0,1,2 -> flat bits 15,14,13.
//
// 2-pass structure (512KB/element canonical state st[f] in d_ws):
//   P1 k_all (outer=f13..15, 1024 thr, 8 amps/thr, WRITE-only):
//     - generation with chain1 folded (b_pre[j]=f_j^f_{j+1}) + Rz1;
//       Ry2(13..15)+CN2(15->14),(14->13) folded analytically into K4[f0,f12]
//     - 6 compute trips, 3-bit windows stride 2:
//        A i={f10,f11,f12}: Ry2(10..12), CN2(13->12)[ctrl o13],(12->11),(11->10),
//                           Rz2(f10..12)+unif(f13,f14), Ry3(11,12)
//        B i={f8,f9,f10}:  Ry2(8,9), CN2(10->9),(9->8), Rz2(f8,f9), Ry3(9,10)
//        C i={f6,f7,f8}:   Ry2(6,7), CN2(8->7),(7->6),  Rz2(f6,f7), Ry3(7,8)
//        D i={f4,f5,f6}:   Ry2(4,5), CN2(6->5),(5->4),  Rz2(f4,f5), Ry3(5,6)
//        E i={f2,f3,f4}:   Ry2(2,3), CN2(4->3),(3->2),  Rz2(f2,f3), Ry3(3,4)
//        F i={f0,f1,f2}:   Ry2(0,1), CN2(2->1),(1->0),  Rz2(f0,f1), Ry3(1,2)
//       (Ry3(j) after CN2(j->j-1) [f_j is its control]; Rz2(j) after CN2(j+1->j).)
//     - trip F layout f = (t<<3)|i is dense -> direct coalesced 64B/thread store.
//   P2 k_fin (outer=f10..12, 256 thr, READ-only, verbatim-verified):
//     CN2(0->15), Rz2(f15), Ry3{0,13,14,15}, measurement with CN3 transported:
//     Z_f15 -> parity(f0..f14); Z_f14 -> f14^f15; Z_f13 -> f13^f14^f15; Rz3 dropped.
// Chunked at 256 elements (128MB) so the P1->P2 handoff is L3-resident.

__device__ __forceinline__ unsigned swz(unsigned l){ return l ^ ((l>>5)&31u); }

__device__ __forceinline__ float2 cmul(float2 a, float2 b){
    return make_float2(a.x*b.x - a.y*b.y, a.x*b.y + a.y*b.x);
}

__device__ __forceinline__ void ry_pair(float2& A0, float2& A1, float c, float s){
    float2 a0=A0, a1=A1;
    A0 = make_float2(c*a0.x - s*a1.x, c*a0.y - s*a1.y);
    A1 = make_float2(s*a0.x + c*a1.x, s*a0.y + c*a1.y);
}

// ---------------- P1: full generation + layer2(- (0->15),Rz2(f15)) + Ry3(1..12)
__global__ __launch_bounds__(1024, 8) void k_all(const float* __restrict__ xg,
                                                 const float* __restrict__ pg,
                                                 float2* __restrict__ st)
{
    __shared__ float2 tile[8192];
    __shared__ float cA[16], sA[16], cB[16], sB[16], cC[16], sC[16], phz1[16], phz2[16];
    __shared__ float2 K4[4], D1[8], EA[8], EB[4], EC[4], ED[4], EE[4], EF[4];
    const int tid = threadIdx.x;
    const int b = blockIdx.x >> 3;
    const unsigned outer = blockIdx.x & 7u;        // f13..15 (post-fold basis)

    // ---- stage 1: angle tables
    if (tid < 16){
        int j = tid, q = 15 - j;
        float th = 0.5f*(xg[b*16+q]*PI_F + pg[q]);           // Ry1
        __sincosf(th, &sA[j], &cA[j]);
    } else if (tid < 32){
        int j = tid-16, q = 15 - j;
        float th = 0.5f*(xg[b*16+q]*PI_F + pg[32+q]);        // Ry2
        __sincosf(th, &sB[j], &cB[j]);
    } else if (tid < 48){
        int j = tid-32, q = 15 - j;
        float th = 0.5f*(xg[b*16+q]*PI_F + pg[64+q]);        // Ry3
        __sincosf(th, &sC[j], &cC[j]);
    } else if (tid < 64){
        int j = tid-48, q = 15 - j;
        phz1[j] = 0.5f*pg[16+q];                              // Rz1
    } else if (tid < 80){
        int j = tid-64, q = 15 - j;
        phz2[j] = 0.5f*pg[48+q];                              // Rz2
    }
    __syncthreads();
    // ---- stage 2: block-uniform tables
    if (tid < 4){
        // K4[(f0<<1)|f12]: Ry2(13..15)+CN2(15->14),(14->13) analytic fold (R6/R8-verified)
        const unsigned o13=outer&1u, o14=(outer>>1)&1u, o15=(outer>>2)&1u;
        const unsigned h13=o13^o14, h14=o14^o15, h15=o15;
        const int f0b=(tid>>1)&1, f12b=tid&1;
        float Kr=0.f, Ki=0.f;
        #pragma unroll
        for (int g=0; g<8; ++g){
            const unsigned g13=g&1u, g14=(g>>1)&1u, g15=(g>>2)&1u;
            float w;
            w  = (h13==g13)? cB[13] : (h13? sB[13] : -sB[13]);
            w *= (h14==g14)? cB[14] : (h14? sB[14] : -sB[14]);
            w *= (h15==g15)? cB[15] : (h15? sB[15] : -sB[15]);
            w *= (f12b^(int)g13)?          sA[12]:cA[12];
            w *= ((int)(g13^g14))?         sA[13]:cA[13];
            w *= ((int)g14^f0b^(int)g15)?  sA[14]:cA[14];
            w *= (f0b^(int)g15)?           sA[15]:cA[15];
            float phg = (g13? phz1[13]:-phz1[13]) + (g14? phz1[14]:-phz1[14])
                      + (g15? phz1[15]:-phz1[15]);
            float sn,cs; __sincosf(phg,&sn,&cs);
            Kr += w*cs; Ki += w*sn;
        }
        K4[tid] = make_float2(Kr,Ki);
    } else if (tid>=16 && tid<24){
        const int ii = tid-16;  // Rz1 over f10..12
        float d=0.f;
        #pragma unroll
        for (int j=0;j<3;j++) d += ((ii>>j)&1)? phz1[10+j]:-phz1[10+j];
        float sn,cs; __sincosf(d,&sn,&cs); D1[ii]=make_float2(cs,sn);
    } else if (tid>=32 && tid<40){
        const int ii = tid-32;  // Rz2 over f10..12 + uniform f13,f14
        float d=0.f;
        #pragma unroll
        for (int j=0;j<3;j++) d += ((ii>>j)&1)? phz2[10+j]:-phz2[10+j];
        d += (outer&1u)?      phz2[13]:-phz2[13];
        d += ((outer>>1)&1u)? phz2[14]:-phz2[14];
        float sn,cs; __sincosf(d,&sn,&cs); EA[ii]=make_float2(cs,sn);
    } else if (tid>=48 && tid<52){
        const int ii = tid-48;  // Rz2 over f8,f9
        float d = ((ii&1)? phz2[8]:-phz2[8]) + (((ii>>1)&1)? phz2[9]:-phz2[9]);
        float sn,cs; __sincosf(d,&sn,&cs); EB[ii]=make_float2(cs,sn);
    } else if (tid>=56 && tid<60){
        const int ii = tid-56;  // Rz2 over f6,f7
        float d = ((ii&1)? phz2[6]:-phz2[6]) + (((ii>>1)&1)? phz2[7]:-phz2[7]);
        float sn,cs; __sincosf(d,&sn,&cs); EC[ii]=make_float2(cs,sn);
    } else if (tid>=64 && tid<68){
        const int ii = tid-64;  // Rz2 over f4,f5
        float d = ((ii&1)? phz2[4]:-phz2[4]) + (((ii>>1)&1)? phz2[5]:-phz2[5]);
        float sn,cs; __sincosf(d,&sn,&cs); ED[ii]=make_float2(cs,sn);
    } else if (tid>=72 && tid<76){
        const int ii = tid-72;  // Rz2 over f2,f3
        float d = ((ii&1)? phz2[2]:-phz2[2]) + (((ii>>1)&1)? phz2[3]:-phz2[3]);
        float sn,cs; __sincosf(d,&sn,&cs); EE[ii]=make_float2(cs,sn);
    } else if (tid>=80 && tid<84){
        const int ii = tid-80;  // Rz2 over f0,f1
        float d = ((ii&1)? phz2[0]:-phz2[0]) + (((ii>>1)&1)? phz2[1]:-phz2[1]);
        float sn,cs; __sincosf(d,&sn,&cs); EF[ii]=make_float2(cs,sn);
    }
    __syncthreads();

    const unsigned t = tid;                 // trip A: t = f0..f9 (10 bits)
    float2 a[8];
    // ---- Trip A generation: i = f10..12
    {
        float base_t = 1.0f;
        #pragma unroll
        for (int j=0;j<9;j++){
            int v = (int)(((t>>j)^(t>>(j+1)))&1u);           // b_pre[j]=f_j^f_{j+1}
            base_t *= v? sA[j]:cA[j];
        }
        float pht = 0.f;
        #pragma unroll
        for (int j=0;j<10;j++) pht += ((t>>j)&1u)? phz1[j]:-phz1[j];
        float Ety,Etx; __sincosf(pht,&Ety,&Etx);
        const float2 Et = make_float2(Etx,Ety);
        const unsigned t0 = t&1u;
        const float2 EK0 = cmul(Et, K4[t0<<1]);
        const float2 EK1 = cmul(Et, K4[(t0<<1)|1u]);
        const int t9 = (int)((t>>9)&1u);
        #pragma unroll
        for (int i=0;i<8;i++){
            const int i0=i&1, i1=(i>>1)&1, i2=(i>>2)&1;
            float pr = base_t;
            pr *= (t9^i0)? sA[9] :cA[9];                     // b_pre[9]=f9^f10
            pr *= (i0^i1)? sA[10]:cA[10];
            pr *= (i1^i2)? sA[11]:cA[11];
            float2 w = cmul(D1[i], i2? EK1:EK0);
            a[i] = make_float2(pr*w.x, pr*w.y);
        }
    }
    // Trip A gates: i0=f10,i1=f11,i2=f12
    #pragma unroll
    for (int j=0;j<8;j++){ if (j&1) continue; ry_pair(a[j],a[j|1],cB[10],sB[10]); }
    #pragma unroll
    for (int j=0;j<8;j++){ if (j&2) continue; ry_pair(a[j],a[j|2],cB[11],sB[11]); }
    #pragma unroll
    for (int j=0;j<8;j++){ if (j&4) continue; ry_pair(a[j],a[j|4],cB[12],sB[12]); }
    if (outer & 1u){  // CN2(13->12): ctrl f13=o13 (uniform), tgt i2
        #pragma unroll
        for (int j=0;j<8;j++){ if (j&4) continue; float2 tm=a[j]; a[j]=a[j|4]; a[j|4]=tm; }
    }
    #pragma unroll
    for (int j=0;j<8;j++){ if (j&2) continue; if ((j>>2)&1){ float2 tm=a[j]; a[j]=a[j|2]; a[j|2]=tm; } } // (12->11)
    #pragma unroll
    for (int j=0;j<8;j++){ if (j&1) continue; if ((j>>1)&1){ float2 tm=a[j]; a[j]=a[j|1]; a[j|1]=tm; } } // (11->10)
    #pragma unroll
    for (int i=0;i<8;i++) a[i] = cmul(a[i], EA[i]);          // Rz2(f10..12)+unif(f13,f14)
    #pragma unroll
    for (int j=0;j<8;j++){ if (j&2) continue; ry_pair(a[j],a[j|2],cC[11],sC[11]); }
    #pragma unroll
    for (int j=0;j<8;j++){ if (j&4) continue; ry_pair(a[j],a[j|4],cC[12],sC[12]); }
    // ---- transpose A -> B
    #pragma unroll
    for (int i=0;i<8;i++) tile[swz(t | ((unsigned)i<<10))] = a[i];
    __syncthreads();
    #pragma unroll
    for (int i=0;i<8;i++) a[i] = tile[swz((t&255u) | ((unsigned)i<<8) | ((t>>8)<<11))];
    // Trip B: i0=f8,i1=f9,i2=f10 ; t&255=f0..7, t>>8=f11,f12
    #pragma unroll
    for (int j=0;j<8;j++){ if (j&1) continue; ry_pair(a[j],a[j|1],cB[8],sB[8]); }
    #pragma unroll
    for (int j=0;j<8;j++){ if (j&2) continue; ry_pair(a[j],a[j|2],cB[9],sB[9]); }
    #pragma unroll
    for (int j=0;j<8;j++){ if (j&2) continue; if ((j>>2)&1){ float2 tm=a[j]; a[j]=a[j|2]; a[j|2]=tm; } } // (10->9)
    #pragma unroll
    for (int j=0;j<8;j++){ if (j&1) continue; if ((j>>1)&1){ float2 tm=a[j]; a[j]=a[j|1]; a[j|1]=tm; } } // (9->8)
    #pragma unroll
    for (int i=0;i<8;i++) a[i] = cmul(a[i], EB[i&3]);        // Rz2(f8,f9)
    #pragma unroll
    for (int j=0;j<8;j++){ if (j&2) continue; ry_pair(a[j],a[j|2],cC[9],sC[9]); }
    #pragma unroll
    for (int j=0;j<8;j++){ if (j&4) continue; ry_pair(a[j],a[j|4],cC[10],sC[10]); }
    // ---- transpose B -> C
    #pragma unroll
    for (int i=0;i<8;i++) tile[swz((t&255u) | ((unsigned)i<<8) | ((t>>8)<<11))] = a[i];
    __syncthreads();
    #pragma unroll
    for (int i=0;i<8;i++) a[i] = tile[swz((t&63u) | ((unsigned)i<<6) | ((t>>6)<<9))];
    // Trip C: i0=f6,i1=f7,i2=f8 ; t&63=f0..5, t>>6=f9..12
    #pragma unroll
    for (int j=0;j<8;j++){ if (j&1) continue; ry_pair(a[j],a[j|1],cB[6],sB[6]); }
    #pragma unroll
    for (int j=0;j<8;j++){ if (j&2) continue; ry_pair(a[j],a[j|2],cB[7],sB[7]); }
    #pragma unroll
    for (int j=0;j<8;j++){ if (j&2) continue; if ((j>>2)&1){ float2 tm=a[j]; a[j]=a[j|2]; a[j|2]=tm; } } // (8->7)
    #pragma unroll
    for (int j=0;j<8;j++){ if (j&1) continue; if ((j>>1)&1){ float2 tm=a[j]; a[j]=a[j|1]; a[j|1]=tm; } } // (7->6)
    #pragma unroll
    for (int i=0;i<8;i++) a[i] = cmul(a[i], EC[i&3]);        // Rz2(f6,f7)
    #pragma unroll
    for (int j=0;j<8;j++){ if (j&2) continue; ry_pair(a[j],a[j|2],cC[7],sC[7]); }
    #pragma unroll
    for (int j=0;j<8;j++){ if (j&4) continue; ry_pair(a[j],a[j|4],cC[8],sC[8]); }
    // ---- transpose C -> D
    #pragma unroll
    for (int i=0;i<8;i++) tile[swz((t&63u) | ((unsigned)i<<6) | ((t>>6)<<9))] = a[i];
    __syncthreads();
    #pragma unroll
    for (int i=0;i<8;i++) a[i] = tile[swz((t&15u) | ((unsigned)i<<4) | ((t>>4)<<7))];
    // Trip D: i0=f4,i1=f5,i2=f6 ; t&15=f0..3, t>>4=f7..12
    #pragma unroll
    for (int j=0;j<8;j++){ if (j&1) continue; ry_pair(a[j],a[j|1],cB[4],sB[4]); }
    #pragma unroll
    for (int j=0;j<8;j++){ if (j&2) continue; ry_pair(a[j],a[j|2],cB[5],sB[5]); }
    #pragma unroll
    for (int j=0;j<8;j++){ if (j&2) continue; if ((j>>2)&1){ float2 tm=a[j]; a[j]=a[j|2]; a[j|2]=tm; } } // (6->5)
    #pragma unroll
    for (int j=0;j<8;j++){ if (j&1) continue; if ((j>>1)&1){ float2 tm=a[j]; a[j]=a[j|1]; a[j|1]=tm; } } // (5->4)
    #pragma unroll
    for (int i=0;i<8;i++) a[i] = cmul(a[i], ED[i&3]);        // Rz2(f4,f5)
    #pragma unroll
    for (int j=0;j<8;j++){ if (j&2) continue; ry_pair(a[j],a[j|2],cC[5],sC[5]); }
    #pragma unroll
    for (int j=0;j<8;j++){ if (j&4) continue; ry_pair(a[j],a[j|4],cC[6],sC[6]); }
    // ---- transpose D -> E
    #pragma unroll
    for (int i=0;i<8;i++) tile[swz((t&15u) | ((unsigned)i<<4) | ((t>>4)<<7))] = a[i];
    __syncthreads();
    #pragma unroll
    for (int i=0;i<8;i++) a[i] = tile[swz((t&3u) | ((unsigned)i<<2) | ((t>>2)<<5))];
    // Trip E: i0=f2,i1=f3,i2=f4 ; t&3=f0,f1, t>>2=f5..12
    #pragma unroll
    for (int j=0;j<8;j++){ if (j&1) continue; ry_pair(a[j],a[j|1],cB[2],sB[2]); }
    #pragma unroll
    for (int j=0;j<8;j++){ if (j&2) continue; ry_pair(a[j],a[j|2],cB[3],sB[3]); }
    #pragma unroll
    for (int j=0;j<8;j++){ if (j&2) continue; if ((j>>2)&1){ float2 tm=a[j]; a[j]=a[j|2]; a[j|2]=tm; } } // (4->3)
    #pragma unroll
    for (int j=0;j<8;j++){ if (j&1) continue; if ((j>>1)&1){ float2 tm=a[j]; a[j]=a[j|1]; a[j|1]=tm; } } // (3->2)
    #pragma unroll
    for (int i=0;i<8;i++) a[i] = cmul(a[i], EE[i&3]);        // Rz2(f2,f3)
    #pragma unroll
    for (int j=0;j<8;j++){ if (j&2) continue; ry_pair(a[j],a[j|2],cC[3],sC[3]); }
    #pragma unroll
    for (int j=0;j<8;j++){ if (j&4) continue; ry_pair(a[j],a[j|4],cC[4],sC[4]); }
    // ---- transpose E -> F
    #pragma unroll
    for (int i=0;i<8;i++) tile[swz((t&3u) | ((unsigned)i<<2) | ((t>>2)<<5))] = a[i];
    __syncthreads();
    #pragma unroll
    for (int i=0;i<8;i++) a[i] = tile[swz((unsigned)i | (t<<3))];
    // Trip F: i0=f0,i1=f1,i2=f2 ; t=f3..12
    #pragma unroll
    for (int j=0;j<8;j++){ if (j&1) continue; ry_pair(a[j],a[j|1],cB[0],sB[0]); }
    #pragma unroll
    for (int j=0;j<8;j++){ if (j&2) continue; ry_pair(a[j],a[j|2],cB[1],sB[1]); }
    #pragma unroll
    for (int j=0;j<8;j++){ if (j&2) continue; if ((j>>2)&1){ float2 tm=a[j]; a[j]=a[j|2]; a[j|2]=tm; } } // (2->1)
    #pragma unroll
    for (int j=0;j<8;j++){ if (j&1) continue; if ((j>>1)&1){ float2 tm=a[j]; a[j]=a[j|1]; a[j|1]=tm; } } // (1->0)
    #pragma unroll
    for (int i=0;i<8;i++) a[i] = cmul(a[i], EF[i&3]);        // Rz2(f0,f1)
    #pragma unroll
    for (int j=0;j<8;j++){ if (j&2) continue; ry_pair(a[j],a[j|2],cC[1],sC[1]); }
    #pragma unroll
    for (int j=0;j<8;j++){ if (j&4) continue; ry_pair(a[j],a[j|4],cC[2],sC[2]); }
    // ---- store: trip F layout f = (t<<3)|i is dense -> direct coalesced store
    float2* sp = st + ((size_t)b<<16);
    float4* d4 = (float4*)(sp + ((t<<3) | (outer<<13)));
    d4[0]=make_float4(a[0].x,a[0].y,a[1].x,a[1].y);
    d4[1]=make_float4(a[2].x,a[2].y,a[3].x,a[3].y);
    d4[2]=make_float4(a[4].x,a[4].y,a[5].x,a[5].y);
    d4[3]=make_float4(a[6].x,a[6].y,a[7].x,a[7].y);
}

// ---------------- P2 k_fin (B-type, outer = f10..12, READ, no LDS tile) — verbatim
__global__ __launch_bounds__(256) void k_fin(const float* __restrict__ xg,
                                             const float* __restrict__ pg,
                                             const float2* __restrict__ st,
                                             float* __restrict__ outg)
{
    __shared__ float cN[16], sN[16];
    __shared__ float snp, csp;
    __shared__ float red[4][3];
    const int tid = threadIdx.x;
    const int b = blockIdx.x >> 3;
    const unsigned outer = blockIdx.x & 7u;        // f bits 10..12
    if (tid < 16){
        int j=tid, q=15-j;
        float th = 0.5f*(xg[b*16+q]*PI_F + pg[64 + q]);      // Ry3
        float s,c; __sincosf(th,&s,&c);
        cN[j]=c; sN[j]=s;
    }
    if (tid==16){ float phi = 0.5f*pg[48 + 0]; float s,c; __sincosf(phi,&s,&c); snp=s; csp=c; }
    __syncthreads();
    const unsigned t = tid;
    const float2* sp = st + ((size_t)b<<16);
    float2 a[32];
    #pragma unroll
    for (int u=0;u<8;u++){
        unsigned fb = (t<<2) | (outer<<10) | ((unsigned)u<<13);
        const float4* s4 = (const float4*)(sp + fb);
        float4 v0=s4[0], v1=s4[1];
        a[4*u+0]=make_float2(v0.x,v0.y); a[4*u+1]=make_float2(v0.z,v0.w);
        a[4*u+2]=make_float2(v1.x,v1.y); a[4*u+3]=make_float2(v1.z,v1.w);
    }
    // CN2(0->15): ctrl f0 = i0, tgt f15 = i4
    #pragma unroll
    for (int j=0;j<32;j++){ if (j&16) continue; if (j&1){ float2 tm=a[j]; a[j]=a[j|16]; a[j|16]=tm; } }
    // Rz2(f15)
    #pragma unroll
    for (int j=0;j<32;j++){
        float sn = ((j>>4)&1)? snp : -snp;
        float2 v=a[j];
        a[j]=make_float2(v.x*csp - v.y*sn, v.x*sn + v.y*csp);
    }
    #pragma unroll
    for (int j=0;j<32;j++){ if (j&1)  continue; ry_pair(a[j],a[j|1] ,cN[0] ,sN[0]);  }
    #pragma unroll
    for (int j=0;j<32;j++){ if (j&4)  continue; ry_pair(a[j],a[j|4] ,cN[13],sN[13]); }
    #pragma unroll
    for (int j=0;j<32;j++){ if (j&8)  continue; ry_pair(a[j],a[j|8] ,cN[14],sN[14]); }
    #pragma unroll
    for (int j=0;j<32;j++){ if (j&16) continue; ry_pair(a[j],a[j|16],cN[15],sN[15]); }
    const int pto = (__popc(t) + __popc(outer)) & 1;   // parity(f2..f12)
    float v0=0.f, v1=0.f, v2=0.f;
    #pragma unroll
    for (int i=0;i<32;i++){
        const int i0=i&1, i1=(i>>1)&1, i2=(i>>2)&1, i3=(i>>3)&1, i4=(i>>4)&1;
        const float pr = a[i].x*a[i].x + a[i].y*a[i].y;
        v0 += (i0^i1^i2^i3^pto)? -pr : pr;   // parity(f0..f14)
        v1 += (i3^i4)?           -pr : pr;   // f14^f15
        v2 += (i2^i3^i4)?        -pr : pr;   // f13^f14^f15
    }
    #pragma unroll
    for (int off=32; off>0; off>>=1){
        v0 += __shfl_down(v0, off);
        v1 += __shfl_down(v1, off);
        v2 += __shfl_down(v2, off);
    }
    const int wv = tid>>6, ln = tid&63;
    if (ln==0){ red[wv][0]=v0; red[wv][1]=v1; red[wv][2]=v2; }
    __syncthreads();
    if (tid<3){
        float s = red[0][tid]+red[1][tid]+red[2][tid]+red[3][tid];
        atomicAdd(&outg[b*3+tid], s);
    }
}

extern "C" void kernel_launch(void* const* d_in, const int* in_sizes, int n_in,
                              void* d_out, int out_size, void* d_ws, size_t ws_size,
                              hipStream_t stream)
{
    const float* x = (const float*)d_in[0];
    const float* params = (const float*)d_in[1];
    float* out = (float*)d_out;
    float2* st = (float2*)d_ws;
    const int B = in_sizes[0] / 16;

    hipMemsetAsync(d_out, 0, (size_t)out_size*sizeof(float), stream);

    const size_t per = (size_t)65536 * sizeof(float2);   // 512 KB per batch element
    int chunk = (int)(ws_size / per);
    if (chunk > 256) chunk = 256;                        // 128 MB -> L3-resident handoff
    if (chunk < 1) chunk = 1;
    if (chunk > B) chunk = B;
    for (int b0=0; b0<B; b0+=chunk){
        const int nb = (B-b0 < chunk) ? (B-b0) : chunk;
        const float* xb = x + (size_t)b0*16;
        float* ob = out + (size_t)b0*3;
        hipLaunchKernelGGL(k_all, dim3(nb*8), dim3(1024), 0, stream, xb, params, st);
        hipLaunchKernelGGL(k_fin, dim3(nb*8), dim3(256), 0, stream, xb, params, st, ob);
    }
}